// Round 2
// baseline (396.031 us; speedup 1.0000x reference)
//
#include <hip/hip_runtime.h>
#include <hip/hip_bf16.h>

typedef unsigned short ushort_t;
typedef __attribute__((ext_vector_type(8))) short short8;
typedef __attribute__((ext_vector_type(4))) float f32x4;
typedef __attribute__((ext_vector_type(4))) unsigned int uint32x4;

#define MFMA16(a, b, c) __builtin_amdgcn_mfma_f32_16x16x32_bf16((a), (b), (c), 0, 0, 0)

__device__ __forceinline__ ushort_t f2bf(float f) {
  unsigned int u = __builtin_bit_cast(unsigned int, f);
  u += 0x7FFFu + ((u >> 16) & 1u);   // round-to-nearest-even
  return (ushort_t)(u >> 16);
}
__device__ __forceinline__ unsigned int pack2bf(float a, float b) {
  unsigned int ua = __builtin_bit_cast(unsigned int, a);
  unsigned int ub = __builtin_bit_cast(unsigned int, b);
  ua += 0x7FFFu + ((ua >> 16) & 1u);
  ub += 0x7FFFu + ((ub >> 16) & 1u);
  return (ua >> 16) | (ub & 0xFFFF0000u);
}

#define DMdim 1024
#define DPdim 128
#define PPdim 256

// workspace layout (ushort element offsets)
#define WQ_ROWS 144                    // 128 Wq rows + gate_w row + 15 zero rows
#define WQ_EXT_OFF 0
#define WO_OFF (WQ_ROWS * DMdim)                 // 147456
#define KB_OFF (WO_OFF + DMdim * DPdim)          // 278528
#define VT_OFF (KB_OFF + PPdim * DPdim)          // 311296
#define CTX_OFF (VT_OFF + PPdim * DPdim)         // 344064, size 32768*128
#define GATE_BYTE_OFF ((size_t)(CTX_OFF + 32768 * DPdim) * 2)  // 9,076,736 B

// ---------------------------------------------------------------------------
// Prep: bf16 weight casts, k = prim@Wk^T, v^T = (prim@Wv^T)^T
// ---------------------------------------------------------------------------
__global__ void prep_kernel(const float* __restrict__ Wq, const float* __restrict__ Wk,
                            const float* __restrict__ Wv, const float* __restrict__ Wo,
                            const float* __restrict__ gate_w, const float* __restrict__ prim,
                            ushort_t* __restrict__ ws) {
  int idx = blockIdx.x * 256 + threadIdx.x;
  if (idx < WQ_ROWS * DMdim) {
    int r = idx >> 10, m = idx & (DMdim - 1);
    float v = (r < DPdim) ? Wq[r * DMdim + m] : (r == DPdim ? gate_w[m] : 0.f);
    ws[WQ_EXT_OFF + idx] = f2bf(v);
    return;
  }
  idx -= WQ_ROWS * DMdim;
  if (idx < DMdim * DPdim) { ws[WO_OFF + idx] = f2bf(Wo[idx]); return; }
  idx -= DMdim * DPdim;
  if (idx < 2 * PPdim * DPdim) {
    bool is_v = idx >= PPdim * DPdim;
    int e = is_v ? idx - PPdim * DPdim : idx;
    int p = e >> 7, d = e & (DPdim - 1);
    const float4* pr = reinterpret_cast<const float4*>(prim + p * DPdim);
    const float4* wr = reinterpret_cast<const float4*>((is_v ? Wv : Wk) + d * DPdim);
    float s = 0.f;
    #pragma unroll
    for (int j = 0; j < DPdim / 4; ++j) {
      float4 a = pr[j], b = wr[j];
      s += a.x * b.x + a.y * b.y + a.z * b.z + a.w * b.w;
    }
    if (is_v) ws[VT_OFF + d * PPdim + p] = f2bf(s);   // v^T[d][p], p-contig over K
    else      ws[KB_OFF + p * DPdim + d] = f2bf(s);   // k[p][d],  d-contig over K
  }
}

// ---------------------------------------------------------------------------
// Kernel (a): per-wave autonomous q/softmax/PV. 16 tokens per wave, NO BARRIERS.
//   q = x@Wq_ext^T (gate logit = col 128), softmax(q k^T * scale), ctx = attn@v.
//   Writes ctx (bf16) + gate (f32) to workspace.
// ---------------------------------------------------------------------------
#define LDQ 136   // q row stride inside per-wave slab (128 + 8 pad)
#define LDA 264   // attn row stride inside per-wave slab (256 + 8 pad)

__global__ __launch_bounds__(256, 2) void attn_kernel(
    const float* __restrict__ x, const float* __restrict__ gate_b,
    const ushort_t* __restrict__ ws, ushort_t* __restrict__ ctx_out,
    float* __restrict__ gate_out)
{
  __shared__ __align__(16) ushort_t smem[4 * 16 * LDA];   // 33,792 B; 4 per-wave slabs

  const ushort_t* wq_ext = ws + WQ_EXT_OFF;
  const ushort_t* k_b    = ws + KB_OFF;
  const ushort_t* v_t    = ws + VT_OFF;

  const int tid  = threadIdx.x;
  const int wid  = tid >> 6;
  const int lane = tid & 63;
  const int quad = lane >> 4;
  const int l16  = lane & 15;
  const int tok0 = blockIdx.x * 64 + wid * 16;
  ushort_t* slab = &smem[wid * 16 * LDA];   // private to this wave → no barriers

  // ---------------- Stage A: q_ext[16][144] = x_rows @ wq_ext^T -------------
  f32x4 qacc[9];
  #pragma unroll
  for (int ct = 0; ct < 9; ++ct) qacc[ct] = (f32x4){0.f, 0.f, 0.f, 0.f};

  const float* xrow = x + (size_t)(tok0 + l16) * DMdim + quad * 8;

  #pragma unroll 4
  for (int kc = 0; kc < DMdim; kc += 32) {
    float4 f0 = *reinterpret_cast<const float4*>(xrow + kc);
    float4 f1 = *reinterpret_cast<const float4*>(xrow + kc + 4);
    uint32x4 pk;
    pk[0] = pack2bf(f0.x, f0.y); pk[1] = pack2bf(f0.z, f0.w);
    pk[2] = pack2bf(f1.x, f1.y); pk[3] = pack2bf(f1.z, f1.w);
    short8 a = __builtin_bit_cast(short8, pk);
    #pragma unroll
    for (int ct = 0; ct < 9; ++ct) {
      short8 b = *reinterpret_cast<const short8*>(
          &wq_ext[(size_t)(ct * 16 + l16) * DMdim + kc + quad * 8]);
      qacc[ct] = MFMA16(a, b, qacc[ct]);
    }
  }

  // gate (from extended column 128 → ct=8, col offset 0 → lanes l16==0)
  if (l16 == 0) {
    float gb = gate_b[0];
    #pragma unroll
    for (int r = 0; r < 4; ++r) {
      float lg = qacc[8][r] + gb;
      gate_out[tok0 + quad * 4 + r] = 1.f / (1.f + __expf(-lg));
    }
  }

  // q (C-layout) -> per-wave LDS slab in A-source layout [tok][128]
  #pragma unroll
  for (int ct = 0; ct < 8; ++ct)
    #pragma unroll
    for (int r = 0; r < 4; ++r)
      slab[(quad * 4 + r) * LDQ + ct * 16 + l16] = f2bf(qacc[ct][r]);

  short8 qa[4];
  #pragma unroll
  for (int k4 = 0; k4 < 4; ++k4)
    qa[k4] = *reinterpret_cast<const short8*>(&slab[l16 * LDQ + k4 * 32 + quad * 8]);

  // ---------------- Stage B: scores[16][256], softmax -----------------------
  f32x4 sacc[16];
  #pragma unroll
  for (int ct = 0; ct < 16; ++ct) sacc[ct] = (f32x4){0.f, 0.f, 0.f, 0.f};
  #pragma unroll
  for (int ct = 0; ct < 16; ++ct)
    #pragma unroll
    for (int k4 = 0; k4 < 4; ++k4) {
      short8 b = *reinterpret_cast<const short8*>(
          &k_b[(size_t)(ct * 16 + l16) * DPdim + k4 * 32 + quad * 8]);
      sacc[ct] = MFMA16(qa[k4], b, sacc[ct]);
    }

  const float SC = 0.08838834764831845f * 1.44269504088896f; // 1/sqrt(128)*log2e
  float rmax[4], rsum[4], inv[4];
  #pragma unroll
  for (int r = 0; r < 4; ++r) rmax[r] = -3.0e38f;
  #pragma unroll
  for (int ct = 0; ct < 16; ++ct)
    #pragma unroll
    for (int r = 0; r < 4; ++r) rmax[r] = fmaxf(rmax[r], sacc[ct][r]);
  #pragma unroll
  for (int m = 1; m < 16; m <<= 1)
    #pragma unroll
    for (int r = 0; r < 4; ++r) rmax[r] = fmaxf(rmax[r], __shfl_xor(rmax[r], m, 64));
  #pragma unroll
  for (int r = 0; r < 4; ++r) rsum[r] = 0.f;
  #pragma unroll
  for (int ct = 0; ct < 16; ++ct)
    #pragma unroll
    for (int r = 0; r < 4; ++r) {
      float e = exp2f((sacc[ct][r] - rmax[r]) * SC);
      sacc[ct][r] = e;
      rsum[r] += e;
    }
  #pragma unroll
  for (int m = 1; m < 16; m <<= 1)
    #pragma unroll
    for (int r = 0; r < 4; ++r) rsum[r] += __shfl_xor(rsum[r], m, 64);
  #pragma unroll
  for (int r = 0; r < 4; ++r) inv[r] = 1.f / rsum[r];

  // attn (C-layout) -> same slab (q reads already done; same-wave lgkmcnt order)
  #pragma unroll
  for (int ct = 0; ct < 16; ++ct)
    #pragma unroll
    for (int r = 0; r < 4; ++r)
      slab[(quad * 4 + r) * LDA + ct * 16 + l16] = f2bf(sacc[ct][r]);

  short8 pa[8];
  #pragma unroll
  for (int k8 = 0; k8 < 8; ++k8)
    pa[k8] = *reinterpret_cast<const short8*>(&slab[l16 * LDA + k8 * 32 + quad * 8]);

  // ---------------- Stage PV: ctx[16][128] = attn @ v -----------------------
  f32x4 cacc[8];
  #pragma unroll
  for (int ct = 0; ct < 8; ++ct) cacc[ct] = (f32x4){0.f, 0.f, 0.f, 0.f};
  #pragma unroll
  for (int ct = 0; ct < 8; ++ct)
    #pragma unroll
    for (int k8 = 0; k8 < 8; ++k8) {
      short8 b = *reinterpret_cast<const short8*>(
          &v_t[(size_t)(ct * 16 + l16) * PPdim + k8 * 32 + quad * 8]);
      cacc[ct] = MFMA16(pa[k8], b, cacc[ct]);
    }

  // ctx (bf16) to workspace, normalized
  #pragma unroll
  for (int ct = 0; ct < 8; ++ct)
    #pragma unroll
    for (int r = 0; r < 4; ++r)
      ctx_out[(size_t)(tok0 + quad * 4 + r) * DPdim + ct * 16 + l16] =
          f2bf(cacc[ct][r] * inv[r]);
}

// ---------------------------------------------------------------------------
// Kernel (b): out[32768][1024] = gate * (ctx @ Wo^T). 32 tokens/block, 4 waves,
// each wave 16 tokens x 512 cols. 1024 blocks -> 16 waves/CU. No LDS.
// ---------------------------------------------------------------------------
__global__ __launch_bounds__(256, 4) void out_kernel(
    const ushort_t* __restrict__ ctx, const float* __restrict__ gate,
    const ushort_t* __restrict__ ws, float* __restrict__ out)
{
  const ushort_t* wo_b = ws + WO_OFF;
  const int tid  = threadIdx.x;
  const int wid  = tid >> 6;
  const int lane = tid & 63;
  const int quad = lane >> 4;
  const int l16  = lane & 15;
  const int tok0 = blockIdx.x * 32 + (wid & 1) * 16;
  const int mc0  = (wid >> 1) * 512;

  short8 ca[4];
  #pragma unroll
  for (int k4 = 0; k4 < 4; ++k4)
    ca[k4] = *reinterpret_cast<const short8*>(
        &ctx[(size_t)(tok0 + l16) * DPdim + k4 * 32 + quad * 8]);
  float g[4];
  #pragma unroll
  for (int r = 0; r < 4; ++r) g[r] = gate[tok0 + quad * 4 + r];

  #pragma unroll 4
  for (int ct = 0; ct < 32; ++ct) {
    const int col0 = mc0 + ct * 16;
    f32x4 oacc = (f32x4){0.f, 0.f, 0.f, 0.f};
    #pragma unroll
    for (int k4 = 0; k4 < 4; ++k4) {
      short8 b = *reinterpret_cast<const short8*>(
          &wo_b[(size_t)(col0 + l16) * DPdim + k4 * 32 + quad * 8]);
      oacc = MFMA16(ca[k4], b, oacc);
    }
    #pragma unroll
    for (int r = 0; r < 4; ++r)
      out[(size_t)(tok0 + quad * 4 + r) * DMdim + col0 + l16] = oacc[r] * g[r];
  }
}

// ---------------------------------------------------------------------------
extern "C" void kernel_launch(void* const* d_in, const int* in_sizes, int n_in,
                              void* d_out, int out_size, void* d_ws, size_t ws_size,
                              hipStream_t stream) {
  const float* x    = (const float*)d_in[0];
  const float* prim = (const float*)d_in[1];
  const float* Wq   = (const float*)d_in[2];
  const float* Wk   = (const float*)d_in[3];
  const float* Wv   = (const float*)d_in[4];
  const float* Wo   = (const float*)d_in[5];
  const float* gw   = (const float*)d_in[6];
  const float* gb   = (const float*)d_in[7];
  float* out = (float*)d_out;
  ushort_t* ws = (ushort_t*)d_ws;
  ushort_t* ctx = ws + CTX_OFF;
  float* gate = (float*)((char*)d_ws + GATE_BYTE_OFF);

  prep_kernel<<<344064 / 256, 256, 0, stream>>>(Wq, Wk, Wv, Wo, gw, prim, ws);
  attn_kernel<<<512, 256, 0, stream>>>(x, gb, ws, ctx, gate);
  out_kernel<<<1024, 256, 0, stream>>>(ctx, gate, ws, out);
}

// Round 3
// 352.383 us; speedup vs baseline: 1.1239x; 1.1239x over previous
//
#include <hip/hip_runtime.h>
#include <hip/hip_bf16.h>

typedef unsigned short ushort_t;
typedef __attribute__((ext_vector_type(8))) short short8;
typedef __attribute__((ext_vector_type(8))) unsigned short ushort8;
typedef __attribute__((ext_vector_type(4))) float f32x4;

#define MFMA16(a,b,c) __builtin_amdgcn_mfma_f32_16x16x32_bf16((a),(b),(c),0,0,0)

__device__ __forceinline__ ushort_t f2bf(float f) {
  unsigned int u = __builtin_bit_cast(unsigned int, f);
  u += 0x7FFFu + ((u >> 16) & 1u);
  return (ushort_t)(u >> 16);
}
__device__ __forceinline__ unsigned int pack2bf(float a, float b) {
  unsigned int ua = __builtin_bit_cast(unsigned int, a);
  unsigned int ub = __builtin_bit_cast(unsigned int, b);
  ua += 0x7FFFu + ((ua >> 16) & 1u);
  ub += 0x7FFFu + ((ub >> 16) & 1u);
  return (ua >> 16) | (ub & 0xFFFF0000u);
}

// Problem dims
#define DMd 1024
#define DPd 128
#define PPd 256

// Workspace layout (ushort element offsets unless noted)
// KWqExt fragments: [chunk 8][ct 17][k4 4][lane 64][8]  (272 x 1024 bf16)
#define KWQ_OFF 0
#define KWQ_SIZE (8*17*4*512)          // 278528
// VWo fragments: [ctg 64][k8 8][lane 64][8]             (256 x 1024 bf16)
#define VWO_OFF KWQ_SIZE
#define VWO_SIZE (64*8*512)            // 262144
#define KV_BYTE_OFF ((size_t)(KWQ_SIZE + VWO_SIZE) * 2)  // 1,081,344 B; then k,v fp32

// ---------------------------------------------------------------------------
// prep1: k = prim @ Wk^T, v = prim @ Wv^T  (fp32, [256][128] each)
// ---------------------------------------------------------------------------
__global__ void prep1_kernel(const float* __restrict__ prim, const float* __restrict__ Wk,
                             const float* __restrict__ Wv, ushort_t* __restrict__ ws) {
  float* kf = (float*)((char*)ws + KV_BYTE_OFF);
  float* vf = kf + 32768;
  int idx = blockIdx.x * 256 + threadIdx.x;      // 65536 total
  int mat = idx >> 15, rem = idx & 32767;
  int p = rem >> 7, d = rem & 127;
  const float4* pr = (const float4*)(prim + p * 128);
  const float4* wr = (const float4*)((mat ? Wv : Wk) + d * 128);
  float s0 = 0.f, s1 = 0.f;
  #pragma unroll
  for (int j = 0; j < 32; j += 2) {
    float4 a = pr[j], b = wr[j];
    s0 += a.x*b.x + a.y*b.y + a.z*b.z + a.w*b.w;
    float4 a2 = pr[j+1], b2 = wr[j+1];
    s1 += a2.x*b2.x + a2.y*b2.y + a2.z*b2.z + a2.w*b2.w;
  }
  (mat ? vf : kf)[rem] = s0 + s1;
}

// ---------------------------------------------------------------------------
// prep2: blocks 0..67  -> KWqExt = k @ Wq (row 256 = gate_w, 257..271 = 0), frag-major
//        blocks 68..131 -> VWo = v @ Wo^T, frag-major
// ---------------------------------------------------------------------------
__global__ void prep2_kernel(const float* __restrict__ Wq, const float* __restrict__ Wo,
                             const float* __restrict__ gate_w, ushort_t* __restrict__ ws) {
  const float* kf = (const float*)((const char*)ws + KV_BYTE_OFF);
  const float* vf = kf + 32768;
  const int b = blockIdx.x, t = threadIdx.x;
  if (b < 68) {
    // p-tile (b>>2)*16, m-slice (b&3)*256; thread: p = p0 + t>>4, m = m0 + (t&15)*16 .. +16
    const int p  = (b >> 2) * 16 + (t >> 4);
    const int m0 = (b & 3) * 256 + (t & 15) * 16;
    float acc[16];
    #pragma unroll
    for (int j = 0; j < 16; ++j) acc[j] = 0.f;
    if (p < 256) {
      const float* kp = kf + p * 128;
      for (int d = 0; d < 128; ++d) {
        float kv = kp[d];
        const float4* wr = (const float4*)(Wq + (size_t)d * 1024 + m0);
        #pragma unroll
        for (int q = 0; q < 4; ++q) {
          float4 w = wr[q];
          acc[q*4+0] += kv * w.x; acc[q*4+1] += kv * w.y;
          acc[q*4+2] += kv * w.z; acc[q*4+3] += kv * w.w;
        }
      }
    } else if (p == 256) {
      #pragma unroll
      for (int j = 0; j < 16; ++j) acc[j] = gate_w[m0 + j];
    } // p>256 stays 0
    const int ct = p >> 4, l16p = p & 15;
    const int c = m0 >> 7, k4 = (m0 >> 5) & 3, q0 = (m0 >> 3) & 3;
    ushort8 u0, u1;
    #pragma unroll
    for (int j = 0; j < 8; ++j) { u0[j] = f2bf(acc[j]); u1[j] = f2bf(acc[8+j]); }
    size_t base = ((size_t)(c * 17 + ct) * 4 + k4) * 512;
    *(ushort8*)&ws[KWQ_OFF + base + (size_t)(q0 * 16 + l16p) * 8]       = u0;
    *(ushort8*)&ws[KWQ_OFF + base + (size_t)((q0 + 1) * 16 + l16p) * 8] = u1;
  } else {
    __shared__ float vs[16 * 128];
    const int bb = b - 68;
    const int p0 = (bb >> 2) * 16;
    const int m  = (bb & 3) * 256 + t;
    {
      int row = t >> 4, col = (t & 15) * 8;
      const float4* src = (const float4*)(vf + (p0 + row) * 128 + col);
      float4 a0 = src[0], a1 = src[1];
      *(float4*)&vs[row * 128 + col]     = a0;
      *(float4*)&vs[row * 128 + col + 4] = a1;
    }
    __syncthreads();
    float acc[16];
    #pragma unroll
    for (int j = 0; j < 16; ++j) acc[j] = 0.f;
    const float4* wr = (const float4*)(Wo + (size_t)m * 128);
    for (int d4 = 0; d4 < 32; ++d4) {
      float4 w = wr[d4];
      #pragma unroll
      for (int pp = 0; pp < 16; ++pp) {
        float4 v4 = *(const float4*)&vs[pp * 128 + d4 * 4];
        acc[pp] += w.x*v4.x + w.y*v4.y + w.z*v4.z + w.w*v4.w;
      }
    }
    const int ctg = m >> 4, l16m = m & 15;
    ushort8 u0, u1;
    #pragma unroll
    for (int j = 0; j < 8; ++j) { u0[j] = f2bf(acc[j]); u1[j] = f2bf(acc[8+j]); }
    const int pA = p0, pB = p0 + 8;
    *(ushort8*)&ws[VWO_OFF + ((size_t)(ctg*8 + (pA>>5))*512) + (size_t)(((pA>>3)&3)*16 + l16m)*8] = u0;
    *(ushort8*)&ws[VWO_OFF + ((size_t)(ctg*8 + (pB>>5))*512) + (size_t)(((pB>>3)&3)*16 + l16m)*8] = u1;
  }
}

// ---------------------------------------------------------------------------
// fused: per block 64 tokens.
//   scores[64,272] = x_tile @ KWqExt^T  (ct-split across 4 waves, B coalesced frag-major)
//   cross-wave softmax (cols 0..255), gate from col 256
//   out[64,1024] = gate * (attn @ VWo)  (wave w owns cols [w*256,+256))
// ---------------------------------------------------------------------------
#define LDX 136        // x-tile row stride, ushorts (128 + 8 pad)
#define LDSLAB 264     // attn slab row stride, ushorts (256 + 8 pad)

__global__ __launch_bounds__(256, 2) void fused_kernel(
    const float* __restrict__ x, const float* __restrict__ gate_b,
    const ushort_t* __restrict__ ws, float* __restrict__ out)
{
  __shared__ __align__(16) char smem[64 * LDSLAB * 2 + 64 * 4 * 4 * 2 + 64 * 4];
  ushort_t* xt       = (ushort_t*)smem;                       // [64][136] (k-loop phase)
  ushort_t* slab     = (ushort_t*)smem;                       // [64][264] (attn phase)
  float*    pmax     = (float*)(smem + 64 * LDSLAB * 2);      // [64][4]
  float*    psum     = pmax + 256;                            // [64][4]
  float*    gate_lds = psum + 256;                            // [64]

  const int t = threadIdx.x, wid = t >> 6, lane = t & 63;
  const int quad = lane >> 4, l16 = lane & 15;
  const int tok0 = blockIdx.x * 64;

  f32x4 acc[4][5];
  #pragma unroll
  for (int rt = 0; rt < 4; ++rt)
    #pragma unroll
    for (int ctl = 0; ctl < 5; ++ctl) acc[rt][ctl] = (f32x4){0.f,0.f,0.f,0.f};

  // ---------------- scores GEMM: 8 chunks of BK=128 -------------------------
  for (int c = 0; c < 8; ++c) {
    if (c) __syncthreads();
    // stage x chunk [64][128] fp32 -> bf16 xt (coalesced: 1KB/wave/instr)
    #pragma unroll
    for (int i = 0; i < 8; ++i) {
      int flat = i * 1024 + t * 4;
      int row = flat >> 7, col = flat & 127;
      float4 f = *(const float4*)(x + (size_t)(tok0 + row) * 1024 + c * 128 + col);
      unsigned int pk0 = pack2bf(f.x, f.y), pk1 = pack2bf(f.z, f.w);
      unsigned long long dv = (unsigned long long)pk0 | ((unsigned long long)pk1 << 32);
      *(unsigned long long*)&xt[row * LDX + col] = dv;
    }
    __syncthreads();
    #pragma unroll
    for (int k4 = 0; k4 < 4; ++k4) {
      short8 a[4];
      #pragma unroll
      for (int rt = 0; rt < 4; ++rt)
        a[rt] = *(const short8*)&xt[(rt * 16 + l16) * LDX + k4 * 32 + quad * 8];
      #pragma unroll
      for (int ctl = 0; ctl < 5; ++ctl) {
        if (ctl == 4 && wid != 3) continue;     // wave-uniform branch
        const int ct = wid * 4 + ctl;
        short8 bfr = *(const short8*)&ws[KWQ_OFF +
            ((size_t)(c * 17 + ct) * 4 + k4) * 512 + (size_t)lane * 8];
        #pragma unroll
        for (int rt = 0; rt < 4; ++rt) acc[rt][ctl] = MFMA16(a[rt], bfr, acc[rt][ctl]);
      }
    }
  }

  // ---------------- cross-wave softmax --------------------------------------
  const float SC = 0.08838834764831845f * 1.44269504088896f;  // 1/sqrt(128) * log2e
  float Mx[4][4];
  #pragma unroll
  for (int rt = 0; rt < 4; ++rt)
    #pragma unroll
    for (int r = 0; r < 4; ++r) {
      float m = acc[rt][0][r];
      #pragma unroll
      for (int ctl = 1; ctl < 4; ++ctl) m = fmaxf(m, acc[rt][ctl][r]);
      #pragma unroll
      for (int msk = 1; msk < 16; msk <<= 1) m = fmaxf(m, __shfl_xor(m, msk, 64));
      Mx[rt][r] = m;
    }
  if (l16 == 0) {
    #pragma unroll
    for (int rt = 0; rt < 4; ++rt)
      #pragma unroll
      for (int r = 0; r < 4; ++r)
        pmax[(rt * 16 + quad * 4 + r) * 4 + wid] = Mx[rt][r];
  }
  __syncthreads();   // barrier: pmax complete (also closes last xt reads)
  float Mf[4][4];
  #pragma unroll
  for (int rt = 0; rt < 4; ++rt)
    #pragma unroll
    for (int r = 0; r < 4; ++r) {
      f32x4 pm = *(f32x4*)&pmax[(rt * 16 + quad * 4 + r) * 4];
      Mf[rt][r] = fmaxf(fmaxf(pm[0], pm[1]), fmaxf(pm[2], pm[3]));
    }
  float Sm[4][4];
  #pragma unroll
  for (int rt = 0; rt < 4; ++rt)
    #pragma unroll
    for (int r = 0; r < 4; ++r) Sm[rt][r] = 0.f;
  #pragma unroll
  for (int rt = 0; rt < 4; ++rt)
    #pragma unroll
    for (int ctl = 0; ctl < 4; ++ctl)
      #pragma unroll
      for (int r = 0; r < 4; ++r) {
        float e = exp2f((acc[rt][ctl][r] - Mf[rt][r]) * SC);
        acc[rt][ctl][r] = e;
        Sm[rt][r] += e;
      }
  #pragma unroll
  for (int rt = 0; rt < 4; ++rt)
    #pragma unroll
    for (int r = 0; r < 4; ++r) {
      #pragma unroll
      for (int msk = 1; msk < 16; msk <<= 1) Sm[rt][r] += __shfl_xor(Sm[rt][r], msk, 64);
    }
  if (l16 == 0) {
    #pragma unroll
    for (int rt = 0; rt < 4; ++rt)
      #pragma unroll
      for (int r = 0; r < 4; ++r)
        psum[(rt * 16 + quad * 4 + r) * 4 + wid] = Sm[rt][r];
    if (wid == 3) {
      float gb = gate_b[0];
      #pragma unroll
      for (int rt = 0; rt < 4; ++rt)
        #pragma unroll
        for (int r = 0; r < 4; ++r) {
          float lg = acc[rt][4][r] + gb;   // raw score, col 256 (l16==0)
          gate_lds[rt * 16 + quad * 4 + r] = 1.f / (1.f + __expf(-lg));
        }
    }
  }
  __syncthreads();   // barrier: psum + gate complete
  float inv[4][4];
  #pragma unroll
  for (int rt = 0; rt < 4; ++rt)
    #pragma unroll
    for (int r = 0; r < 4; ++r) {
      f32x4 ps = *(f32x4*)&psum[(rt * 16 + quad * 4 + r) * 4];
      inv[rt][r] = 1.f / (ps[0] + ps[1] + ps[2] + ps[3]);
    }

  // attn -> shared slab (each wave writes its ct columns)
  #pragma unroll
  for (int rt = 0; rt < 4; ++rt)
    #pragma unroll
    for (int ctl = 0; ctl < 4; ++ctl)
      #pragma unroll
      for (int r = 0; r < 4; ++r)
        slab[(rt * 16 + quad * 4 + r) * LDSLAB + (wid * 4 + ctl) * 16 + l16] =
            f2bf(acc[rt][ctl][r] * inv[rt][r]);
  __syncthreads();   // barrier: slab complete

  // ---------------- out GEMM: attn @ VWo, wave w owns cols [w*256, +256) ----
  short8 af[4][8];
  #pragma unroll
  for (int rt = 0; rt < 4; ++rt)
    #pragma unroll
    for (int k8 = 0; k8 < 8; ++k8)
      af[rt][k8] = *(const short8*)&slab[(rt * 16 + l16) * LDSLAB + k8 * 32 + quad * 8];
  float g[4][4];
  #pragma unroll
  for (int rt = 0; rt < 4; ++rt)
    #pragma unroll
    for (int r = 0; r < 4; ++r) g[rt][r] = gate_lds[rt * 16 + quad * 4 + r];

  const int n0 = wid * 256;
  for (int nt = 0; nt < 16; ++nt) {
    const int ctg = (n0 >> 4) + nt;
    short8 bf[8];
    #pragma unroll
    for (int k8 = 0; k8 < 8; ++k8)
      bf[k8] = *(const short8*)&ws[VWO_OFF + ((size_t)(ctg * 8 + k8) * 512) + (size_t)lane * 8];
    f32x4 oa[4];
    #pragma unroll
    for (int rt = 0; rt < 4; ++rt) oa[rt] = (f32x4){0.f,0.f,0.f,0.f};
    #pragma unroll
    for (int rt = 0; rt < 4; ++rt)
      #pragma unroll
      for (int k8 = 0; k8 < 8; ++k8)
        oa[rt] = MFMA16(af[rt][k8], bf[k8], oa[rt]);
    #pragma unroll
    for (int rt = 0; rt < 4; ++rt)
      #pragma unroll
      for (int r = 0; r < 4; ++r)
        out[(size_t)(tok0 + rt * 16 + quad * 4 + r) * 1024 + n0 + nt * 16 + l16] =
            oa[rt][r] * g[rt][r];
  }
}

// ---------------------------------------------------------------------------
extern "C" void kernel_launch(void* const* d_in, const int* in_sizes, int n_in,
                              void* d_out, int out_size, void* d_ws, size_t ws_size,
                              hipStream_t stream) {
  const float* x    = (const float*)d_in[0];
  const float* prim = (const float*)d_in[1];
  const float* Wq   = (const float*)d_in[2];
  const float* Wk   = (const float*)d_in[3];
  const float* Wv   = (const float*)d_in[4];
  const float* Wo   = (const float*)d_in[5];
  const float* gw   = (const float*)d_in[6];
  const float* gb   = (const float*)d_in[7];
  float* out = (float*)d_out;
  ushort_t* ws = (ushort_t*)d_ws;

  prep1_kernel<<<256, 256, 0, stream>>>(prim, Wk, Wv, ws);
  prep2_kernel<<<132, 256, 0, stream>>>(Wq, Wo, gw, ws);
  fused_kernel<<<512, 256, 0, stream>>>(x, gb, ws, out);
}